// Round 5
// baseline (93.631 us; speedup 1.0000x reference)
//
#include <hip/hip_runtime.h>

// out: 4 tensors (32, 20, 14, 14, 14, 14) fp32 concatenated.
// Block = (n, d2, qg); handles q = qg + 5j, j=0..3. For fixed (n,d2):
//   out_p(i,j)[q,d3,ps] = Fc_i[d3,ps] * kq_i[q,d3] * U_j[ps] * x_j[q,ps] * v_j[d3,ps]
//   Fc_i[d3,ps] = 0.5*cor_i[0,pc]*cor_i[23+d4,pc]*cor_i[37+d5,pc]   (q-indep, LDS table)
//   U_j[ps]     = cen_j[0,ps]*cen_j[23+d2,ps]                        (q-indep, LDS)
//   kq_i[q,d3]  = cor_i[1+q,pc]          pc = d2*14+d3               (scalars, LDS)
//   x_j[q,ps]   = cen_j[1+q,ps]          (global, L2-hot)
//   v_j[d3,ps]  = cen_j[37+d3,ps]        (global, L2-hot, q-indep -> hoisted to regs)
// p1=(1,1) p2=(2,1) p3=(1,2) p4=(2,2)

#define S_PER 24586240u
#define TSTRIDE (51 * 196)
#define N_STRIDE (204 * 196)

__global__ __launch_bounds__(256) void plnet_kernel(const float* __restrict__ in,
                                                    float* __restrict__ out) {
    __shared__ __align__(16) float sFc1[2744];   // [d3][ps]
    __shared__ __align__(16) float sFc2[2744];
    __shared__ __align__(16) float sU1[196], sU2[196];
    __shared__ float sA1[196], sA2[196], sB1[196], sB2[196];
    __shared__ float sKq1[56], sKq2[56];         // [j][d3]

    const unsigned b  = blockIdx.x;
    const unsigned qg = b % 5u;
    const unsigned r0 = b / 5u;
    const unsigned d2 = r0 % 14u;
    const unsigned n  = r0 / 14u;

    const float* g    = in + (size_t)n * N_STRIDE;
    const float* cor1 = g;
    const float* cor2 = g + TSTRIDE;
    const float* cen1 = g + 2 * TSTRIDE;
    const float* cen2 = g + 3 * TSTRIDE;

    const unsigned tid = threadIdx.x;

    // ---- Phase 1: small tables ----
    if (tid < 196u) {
        const unsigned ps = tid;
        sU1[ps] = cen1[ps] * cen1[(23u + d2) * 196u + ps];
        sU2[ps] = cen2[ps] * cen2[(23u + d2) * 196u + ps];
        const unsigned d3 = ps / 14u;
        const unsigned k  = ps - d3 * 14u;
        const unsigned pc = d2 * 14u + d3;
        sA1[ps] = 0.5f * cor1[pc] * cor1[(23u + k) * 196u + pc];
        sA2[ps] = 0.5f * cor2[pc] * cor2[(23u + k) * 196u + pc];
        sB1[ps] = cor1[(37u + k) * 196u + pc];
        sB2[ps] = cor2[(37u + k) * 196u + pc];
    }
    if (tid < 112u) {                    // kq scalars: [j=4][i=2][d3=14]
        const unsigned j  = tid / 28u;
        const unsigned r  = tid - 28u * j;
        const unsigned i  = r / 14u;
        const unsigned d3 = r - 14u * i;
        const unsigned q  = qg + 5u * j;
        const unsigned pc = d2 * 14u + d3;
        if (i == 0u) sKq1[j * 14u + d3] = cor1[(1u + q) * 196u + pc];
        else         sKq2[j * 14u + d3] = cor2[(1u + q) * 196u + pc];
    }
    __syncthreads();

    // ---- Phase 2: expand Fc tables (once, reused for 4 q) ----
    for (unsigned c = tid; c < 686u; c += 256u) {
        const unsigned d3 = c / 49u;
        const unsigned f  = c - 49u * d3;
        const unsigned e  = 4u * f;
        unsigned d4 = e / 14u;
        unsigned d5 = e - 14u * d4;
        float f1[4], f2[4];
#pragma unroll
        for (int l = 0; l < 4; ++l) {
            f1[l] = sA1[d3 * 14u + d4] * sB1[d3 * 14u + d5];
            f2[l] = sA2[d3 * 14u + d4] * sB2[d3 * 14u + d5];
            ++d5;
            const unsigned carry = (d5 == 14u);
            d4 += carry;
            d5 = carry ? 0u : d5;
        }
        ((float4*)sFc1)[c] = make_float4(f1[0], f1[1], f1[2], f1[3]);
        ((float4*)sFc2)[c] = make_float4(f2[0], f2[1], f2[2], f2[3]);
    }
    __syncthreads();

    // ---- Hoist per-thread q-independent data into registers ----
    float4 u1h[3], u2h[3], fc1h[3], fc2h[3], v1h[3], v2h[3];
    unsigned d3h[3], eh[3];
#pragma unroll
    for (int k = 0; k < 3; ++k) {
        const unsigned c  = tid + 256u * (unsigned)k;
        const unsigned cc = (c < 686u) ? c : 0u;
        const unsigned d3 = cc / 49u;
        const unsigned f  = cc - 49u * d3;
        const unsigned e  = 4u * f;
        d3h[k] = d3; eh[k] = e;
        u1h[k]  = *(const float4*)&sU1[e];
        u2h[k]  = *(const float4*)&sU2[e];
        fc1h[k] = ((const float4*)sFc1)[cc];
        fc2h[k] = ((const float4*)sFc2)[cc];
        v1h[k]  = *(const float4*)&cen1[(37u + d3) * 196u + e];
        v2h[k]  = *(const float4*)&cen2[(37u + d3) * 196u + e];
    }

    // ---- Main: 4 q values, no barriers ----
#pragma unroll
    for (unsigned j = 0; j < 4u; ++j) {
        const unsigned q = qg + 5u * j;
        const size_t chunk = ((size_t)(n * 20u + q) * 196u + d2 * 14u) * 196u;
        float4* o1 = (float4*)(out + chunk);
        float4* o2 = (float4*)(out + (size_t)S_PER + chunk);
        float4* o3 = (float4*)(out + 2u * (size_t)S_PER + chunk);
        float4* o4 = (float4*)(out + 3u * (size_t)S_PER + chunk);
        const float* xr1 = &cen1[(1u + q) * 196u];
        const float* xr2 = &cen2[(1u + q) * 196u];

#pragma unroll
        for (int k = 0; k < 3; ++k) {
            const unsigned c = tid + 256u * (unsigned)k;
            if (c < 686u) {
                const float4 x1 = *(const float4*)&xr1[eh[k]];
                const float4 x2 = *(const float4*)&xr2[eh[k]];
                const float kq1 = sKq1[j * 14u + d3h[k]];
                const float kq2 = sKq2[j * 14u + d3h[k]];

                // g_j = U_j * x_j * v_j   (center combos)
                const float4 g1 = make_float4(u1h[k].x * x1.x * v1h[k].x,
                                              u1h[k].y * x1.y * v1h[k].y,
                                              u1h[k].z * x1.z * v1h[k].z,
                                              u1h[k].w * x1.w * v1h[k].w);
                const float4 g2 = make_float4(u2h[k].x * x2.x * v2h[k].x,
                                              u2h[k].y * x2.y * v2h[k].y,
                                              u2h[k].z * x2.z * v2h[k].z,
                                              u2h[k].w * x2.w * v2h[k].w);
                // h_i = Fc_i * kq_i      (corner combos)
                const float4 h1 = make_float4(fc1h[k].x * kq1, fc1h[k].y * kq1,
                                              fc1h[k].z * kq1, fc1h[k].w * kq1);
                const float4 h2 = make_float4(fc2h[k].x * kq2, fc2h[k].y * kq2,
                                              fc2h[k].z * kq2, fc2h[k].w * kq2);

                o1[c] = make_float4(h1.x * g1.x, h1.y * g1.y, h1.z * g1.z, h1.w * g1.w);
                o2[c] = make_float4(h2.x * g1.x, h2.y * g1.y, h2.z * g1.z, h2.w * g1.w);
                o3[c] = make_float4(h1.x * g2.x, h1.y * g2.y, h1.z * g2.z, h1.w * g2.w);
                o4[c] = make_float4(h2.x * g2.x, h2.y * g2.y, h2.z * g2.z, h2.w * g2.w);
            }
        }
    }
}

extern "C" void kernel_launch(void* const* d_in, const int* in_sizes, int n_in,
                              void* d_out, int out_size, void* d_ws, size_t ws_size,
                              hipStream_t stream) {
    const float* in = (const float*)d_in[0];
    float* out = (float*)d_out;
    dim3 grid(32 * 14 * 5);        // (n, d2, qg); qg fastest -> neighbors share tables in L2
    dim3 block(256);
    plnet_kernel<<<grid, block, 0, stream>>>(in, out);
}